// Round 5
// baseline (116.982 us; speedup 1.0000x reference)
//
#include <hip/hip_runtime.h>
#include <hip/hip_bf16.h>

// CustomAttention: proj = tanh(H @ W^T + b); scores = proj @ c; attn = softmax_L(scores);
// out0 = sum_l H * attn ; out1 = attn.
// B=64, L=512, D=768.  M = B*L = 32768 rows.
// Round 5: BK=32 (LDS 33.8 KB/block -> 4 blocks/CU residency, was 2) to fill the
// latency/barrier windows with independent blocks; softmax fused into wsum.

using half8 = __attribute__((ext_vector_type(8))) _Float16;   // MFMA A/B frag (4 VGPRs)
using f32x4 = __attribute__((ext_vector_type(4))) float;      // MFMA C/D frag

#define AS1 __attribute__((address_space(1)))
#define AS3 __attribute__((address_space(3)))

__device__ __forceinline__ void gload_lds16(const void* g, void* l) {
  __builtin_amdgcn_global_load_lds((const AS1 void*)g, (AS3 void*)l, 16, 0, 0);
}

__device__ __forceinline__ unsigned short f2h(float x) {
  _Float16 h = (_Float16)x;                       // v_cvt_f16_f32, RNE
  return __builtin_bit_cast(unsigned short, h);
}

// tanh(x) = 1 - 2/(exp(2x)+1).  __expf -> v_exp_f32; graceful at +/-inf.
__device__ __forceinline__ float tanh_fast(float x) {
  return 1.0f - __fdividef(2.0f, 1.0f + __expf(2.0f * x));
}

// ---------------- conversion kernels ----------------

// H (fp32 [32768][768]) -> Ah (f16 [32768][768])
__global__ void convert_h(const float4* __restrict__ H4, ushort4* __restrict__ Ah) {
  int i = blockIdx.x * 256 + threadIdx.x;   // quad index, 6291456 total
  float4 x = H4[i];
  ushort4 o;
  o.x = f2h(x.x); o.y = f2h(x.y); o.z = f2h(x.z); o.w = f2h(x.w);
  Ah[i] = o;
}

// W (fp32 [768][768]) -> Wt (f16 [768][768])
__global__ void convert_w(const float4* __restrict__ W4, ushort4* __restrict__ Wt) {
  int i = blockIdx.x * 256 + threadIdx.x;   // 147456 quads
  float4 x = W4[i];
  ushort4 o;
  o.x = f2h(x.x); o.y = f2h(x.y); o.z = f2h(x.z); o.w = f2h(x.w);
  Wt[i] = o;
}

// ---------------- fused GEMM + tanh/context epilogue ----------------
// Tile 128(M) x 128(N), BK=32, 256 threads = 4 waves in 2x2, each wave 64x64
// (4x4 frags of mfma_f32_16x16x32_f16, ONE k-slab per step).  24 K-steps,
// double-buffered LDS (2 x 16 KB total): stage step k+1 while computing k,
// one __syncthreads per step.
// LDS tiles [row][32 k] f16 = 64 B rows, XOR swizzle byte ^= (row&3)<<4 applied
// both-sides (pre-swizzled global source + swizzled ds_read): 8 lanes per
// 4-bank group = 2 lanes/bank = conflict-free.
// Grid: flat 1536; XCD-affinity decode (bid&7 = XCD) keeps the 6 same-mtile
// blocks on one XCD -> A-tile L2 reuse (verified r3: FETCH 76->30 MB).

__device__ __forceinline__ void stage_tiles32(const char* abase, const char* bbase,
                                              char* ldsAbuf, char* ldsBbuf, int tid) {
  char* ldsAw = ldsAbuf + ((tid >> 6) << 10);
  char* ldsBw = ldsBbuf + ((tid >> 6) << 10);
  #pragma unroll
  for (int r = 0; r < 2; ++r) {
    int off = tid * 16 + r * 4096;
    int row = off >> 6;
    int col = (off & 63) ^ ((row & 3) << 4);      // inverse-swizzled source
    gload_lds16(abase + row * 1536 + col, ldsAw + r * 4096);
  }
  #pragma unroll
  for (int r = 0; r < 2; ++r) {
    int off = tid * 16 + r * 4096;
    int row = off >> 6;
    int col = (off & 63) ^ ((row & 3) << 4);
    gload_lds16(bbase + row * 1536 + col, ldsBw + r * 4096);
  }
}

__device__ __forceinline__ void compute_tile32(const ushort* ldsAbuf, const ushort* ldsBbuf,
                                               int wr, int wc, int m, int q,
                                               f32x4 acc[4][4]) {
  half8 areg[4], breg[4];
  #pragma unroll
  for (int mi = 0; mi < 4; ++mi) {
    int row = wr * 64 + mi * 16 + m;
    int col = (q * 16) ^ ((row & 3) << 4);        // swizzled read
    areg[mi] = *(const half8*)((const char*)ldsAbuf + row * 64 + col);
  }
  #pragma unroll
  for (int ni = 0; ni < 4; ++ni) {
    int row = wc * 64 + ni * 16 + m;
    int col = (q * 16) ^ ((row & 3) << 4);
    breg[ni] = *(const half8*)((const char*)ldsBbuf + row * 64 + col);
  }
  #pragma unroll
  for (int mi = 0; mi < 4; ++mi)
    #pragma unroll
    for (int ni = 0; ni < 4; ++ni)
      acc[mi][ni] = __builtin_amdgcn_mfma_f32_16x16x32_f16(
          areg[mi], breg[ni], acc[mi][ni], 0, 0, 0);
}

__global__ __launch_bounds__(256, 4) void gemm_scores(
    const ushort* __restrict__ Ah, const ushort* __restrict__ Wt,
    const float* __restrict__ bias, const float* __restrict__ cvec,
    float* __restrict__ part) {
  __shared__ ushort ldsA[2][4096];    // 2 x 8 KB
  __shared__ ushort ldsB[2][4096];    // 2 x 8 KB
  __shared__ float scpart[2][128];

  const int tid = threadIdx.x;
  const int lane = tid & 63;
  const int wid = tid >> 6;           // 0..3
  const int wr = wid >> 1, wc = wid & 1;
  const int m = lane & 15, q = lane >> 4;

  const int bid = blockIdx.x;         // 0..1535
  const int xcd = bid & 7;
  const int slot = bid >> 3;          // 0..191
  const int mtile = xcd * 32 + slot / 6;
  const int ntile = slot % 6;

  f32x4 acc[4][4];
  #pragma unroll
  for (int a = 0; a < 4; ++a)
    #pragma unroll
    for (int b2 = 0; b2 < 4; ++b2)
      acc[a][b2] = (f32x4){0.f, 0.f, 0.f, 0.f};

  const char* const abase0 = (const char*)Ah + (size_t)(mtile * 128) * 1536;
  const char* const bbase0 = (const char*)Wt + (size_t)(ntile * 128) * 1536;

  // prologue: stage k-slab 0 into buffer 0
  stage_tiles32(abase0, bbase0, (char*)ldsA[0], (char*)ldsB[0], tid);
  __syncthreads();

  #pragma unroll
  for (int kb2 = 0; kb2 < 12; ++kb2) {
    // stage slab 2*kb2+1 into buf1 (always exists: kb2<=11 -> kb<=23)
    stage_tiles32(abase0 + (kb2 * 2 + 1) * 64, bbase0 + (kb2 * 2 + 1) * 64,
                  (char*)ldsA[1], (char*)ldsB[1], tid);
    compute_tile32(ldsA[0], ldsB[0], wr, wc, m, q, acc);
    __syncthreads();                  // drains buf1 stage + all buf0 reads

    if (kb2 < 11)
      stage_tiles32(abase0 + (kb2 * 2 + 2) * 64, bbase0 + (kb2 * 2 + 2) * 64,
                    (char*)ldsA[0], (char*)ldsB[0], tid);
    compute_tile32(ldsA[1], ldsB[1], wr, wc, m, q, acc);
    __syncthreads();
  }

  // epilogue: score partial = sum_e tanh(acc + b[e]) * c[e], reduced per row
  float bb[4], cc[4];
  #pragma unroll
  for (int ni = 0; ni < 4; ++ni) {
    int e = ntile * 128 + wc * 64 + ni * 16 + m;
    bb[ni] = bias[e];
    cc[ni] = cvec[e];
  }
  #pragma unroll
  for (int mi = 0; mi < 4; ++mi) {
    #pragma unroll
    for (int j = 0; j < 4; ++j) {
      float s = 0.f;
      #pragma unroll
      for (int ni = 0; ni < 4; ++ni)
        s += tanh_fast(acc[mi][ni][j] + bb[ni]) * cc[ni];
      // reduce across the 16 lanes sharing this C row (lane&15 = e varies)
      s += __shfl_xor(s, 1);
      s += __shfl_xor(s, 2);
      s += __shfl_xor(s, 4);
      s += __shfl_xor(s, 8);
      if (m == 0) scpart[wc][wr * 64 + mi * 16 + q * 4 + j] = s;
    }
  }
  __syncthreads();
  if (tid < 128)
    part[ntile * 32768 + mtile * 128 + tid] = scpart[0][tid] + scpart[1][tid];
}

// ---------------- fused softmax + weighted sum ----------------
// grid (64, 3), 128 threads.  Each block recomputes the softmax over L=512 from
// the 6 score partials (12 KB redundant reads, L2-hot), then does the weighted
// sum for its 256 d-columns.  dc==0 also writes attention_weights.
__global__ void wsum_fused(const ushort* __restrict__ Ah, const float* __restrict__ prt,
                           float* __restrict__ out) {
  int b = blockIdx.x, dc = blockIdx.y;
  int t = threadIdx.x;
  __shared__ float w[512];
  __shared__ float redm[2], reds[2];

  float s[4];
  #pragma unroll
  for (int i = 0; i < 4; ++i) {
    int r = b * 512 + t + i * 128;
    s[i] = prt[r] + prt[32768 + r] + prt[2 * 32768 + r] +
           prt[3 * 32768 + r] + prt[4 * 32768 + r] + prt[5 * 32768 + r];
  }
  float mx = fmaxf(fmaxf(s[0], s[1]), fmaxf(s[2], s[3]));
  #pragma unroll
  for (int o = 32; o >= 1; o >>= 1) mx = fmaxf(mx, __shfl_xor(mx, o));
  if ((t & 63) == 0) redm[t >> 6] = mx;
  __syncthreads();
  mx = fmaxf(redm[0], redm[1]);

  float e[4], sm = 0.f;
  #pragma unroll
  for (int i = 0; i < 4; ++i) { e[i] = __expf(s[i] - mx); sm += e[i]; }
  #pragma unroll
  for (int o = 32; o >= 1; o >>= 1) sm += __shfl_xor(sm, o);
  if ((t & 63) == 0) reds[t >> 6] = sm;
  __syncthreads();
  float inv = 1.0f / (reds[0] + reds[1]);
  #pragma unroll
  for (int i = 0; i < 4; ++i) w[t + i * 128] = e[i] * inv;
  __syncthreads();

  int d0 = dc * 256 + t * 2;
  const ushort* hp = Ah + (size_t)b * 512 * 768 + d0;
  float a0 = 0.f, a1 = 0.f;
  #pragma unroll 8
  for (int l = 0; l < 512; ++l) {
    unsigned u = *(const unsigned*)(hp + (size_t)l * 768);
    float wl = w[l];
    a0 += wl * (float)__builtin_bit_cast(_Float16, (unsigned short)(u & 0xffff));
    a1 += wl * (float)__builtin_bit_cast(_Float16, (unsigned short)(u >> 16));
  }
  out[b * 768 + d0] = a0;
  out[b * 768 + d0 + 1] = a1;

  if (dc == 0) {
    #pragma unroll
    for (int i = 0; i < 4; ++i)
      out[49152 + b * 512 + t + i * 128] = w[t + i * 128];
  }
}

// ---------------- launch ----------------
extern "C" void kernel_launch(void* const* d_in, const int* in_sizes, int n_in,
                              void* d_out, int out_size, void* d_ws, size_t ws_size,
                              hipStream_t stream) {
  const float* H    = (const float*)d_in[0];   // [64,512,768]
  const float* W    = (const float*)d_in[1];   // [768,768]
  const float* bias = (const float*)d_in[2];   // [768]
  const float* cvec = (const float*)d_in[3];   // [768,1]
  float* out = (float*)d_out;                  // [0,49152): weighted ; [49152,81920): attn

  char* ws = (char*)d_ws;
  ushort* Ah = (ushort*)(ws + 0);              // 50,331,648 B
  ushort* Wt = (ushort*)(ws + 50331648);       //  1,179,648 B
  float*  prt = (float*)(ws + 51511296);       //    786,432 B  ([6][32768])

  hipLaunchKernelGGL(convert_h, dim3(24576), dim3(256), 0, stream,
                     (const float4*)H, (ushort4*)Ah);
  hipLaunchKernelGGL(convert_w, dim3(576), dim3(256), 0, stream,
                     (const float4*)W, (ushort4*)Wt);
  hipLaunchKernelGGL(gemm_scores, dim3(1536), dim3(256), 0, stream,
                     Ah, Wt, bias, cvec, prt);
  hipLaunchKernelGGL(wsum_fused, dim3(64, 3), dim3(128), 0, stream,
                     Ah, prt, out);
}

// Round 7
// 111.888 us; speedup vs baseline: 1.0455x; 1.0455x over previous
//
#include <hip/hip_runtime.h>
#include <hip/hip_bf16.h>

// CustomAttention: proj = tanh(H @ W^T + b); scores = proj @ c; attn = softmax_L(scores);
// out0 = sum_l H * attn ; out1 = attn.   B=64, L=512, D=768.  M = B*L = 32768.
// Round 7: counted-vmcnt pipelined GEMM: BM=128 BN=256 BK=64, 8 waves (2Mx4N),
// TRIPLE-buffered K-tile slots (compute t | t+1 resident | stage t+2), 2 phases
// per K-tile, vmcnt(6) once per tile (never 0 until the drain tile), raw
// s_barrier + setprio around 16-MFMA clusters.  LDS = 3*(16+32)+2 = 146 KB.

using half8 = __attribute__((ext_vector_type(8))) _Float16;   // MFMA A/B frag (4 VGPRs)
using f32x4 = __attribute__((ext_vector_type(4))) float;      // MFMA C/D frag

#define AS1 __attribute__((address_space(1)))
#define AS3 __attribute__((address_space(3)))

__device__ __forceinline__ void gload_lds16(const void* g, void* l) {
  __builtin_amdgcn_global_load_lds((const AS1 void*)g, (AS3 void*)l, 16, 0, 0);
}

__device__ __forceinline__ unsigned short f2h(float x) {
  _Float16 h = (_Float16)x;                       // v_cvt_f16_f32, RNE
  return __builtin_bit_cast(unsigned short, h);
}

// tanh(x) = 1 - 2/(exp(2x)+1).
__device__ __forceinline__ float tanh_fast(float x) {
  return 1.0f - __fdividef(2.0f, 1.0f + __expf(2.0f * x));
}

// ---------------- conversion kernels ----------------

__global__ void convert_h(const float4* __restrict__ H4, ushort4* __restrict__ Ah) {
  int i = blockIdx.x * 256 + threadIdx.x;   // 6291456 quads
  float4 x = H4[i];
  ushort4 o;
  o.x = f2h(x.x); o.y = f2h(x.y); o.z = f2h(x.z); o.w = f2h(x.w);
  Ah[i] = o;
}

__global__ void convert_w(const float4* __restrict__ W4, ushort4* __restrict__ Wt) {
  int i = blockIdx.x * 256 + threadIdx.x;   // 147456 quads
  float4 x = W4[i];
  ushort4 o;
  o.x = f2h(x.x); o.y = f2h(x.y); o.z = f2h(x.z); o.w = f2h(x.w);
  Wt[i] = o;
}

// ---------------- pipelined GEMM + tanh/context epilogue ----------------
// LDS rows are 128 B (64 f16), swizzle byte ^= (row&7)<<4 applied both-sides
// (inverse-swizzled global source for gload_lds + swizzled ds_read): 0 conflicts
// (verified r1-r4).  Grid: flat 768; XCD decode (bid&7) keeps the 3 same-mtile
// blocks on one XCD, adjacent slots -> A-tile L2 reuse (verified r3).
__global__ __launch_bounds__(512) void gemm_scores(
    const ushort* __restrict__ Ah, const ushort* __restrict__ Wt,
    const float* __restrict__ bias, const float* __restrict__ cvec,
    float* __restrict__ part) {
  __shared__ ushort ldsA[3][128 * 64];   // 3 x 16 KB = 48 KB
  __shared__ ushort ldsB[3][256 * 64];   // 3 x 32 KB = 96 KB
  __shared__ float scpart[4][128];       // 2 KB

  const int tid = threadIdx.x;
  const int lane = tid & 63;
  const int wid = tid >> 6;             // 0..7
  const int wr = wid >> 2;              // 0..1  (M half: rows wr*64..)
  const int wc = wid & 3;               // 0..3  (N quarter: cols wc*64..)
  const int m = lane & 15, q = lane >> 4;

  const int bid = blockIdx.x;           // 0..767
  const int xcd = bid & 7;
  const int sid = bid >> 3;             // 0..95
  const int mtile = xcd * 32 + sid / 3; // 0..255
  const int ntile = sid % 3;            // 0..2

  const char* const Abase = (const char*)Ah + (size_t)(mtile * 128) * 1536;
  const char* const Bbase = (const char*)Wt + (size_t)(ntile * 256) * 1536;
  const int wavebase = (tid >> 6) << 10;

  f32x4 acc[4][4];
  #pragma unroll
  for (int i = 0; i < 4; ++i)
    #pragma unroll
    for (int j = 0; j < 4; ++j)
      acc[i][j] = (f32x4){0.f, 0.f, 0.f, 0.f};

  // stage A K-tile kt (128 rows x 64k = 16 KB = 2 calls of 512thr x 16B)
  auto stageA = [&](int kt, char* dst) {
    #pragma unroll
    for (int c = 0; c < 2; ++c) {
      int off = tid * 16 + c * 8192;
      int row = off >> 7;
      int col = (off & 127) ^ ((row & 7) << 4);
      gload_lds16(Abase + (size_t)row * 1536 + kt * 128 + col,
                  dst + c * 8192 + wavebase);
    }
  };
  // stage one quarter (c in 0..3) of B K-tile kt (256 rows -> 32 KB)
  auto stageBq = [&](int kt, char* dst, int c) {
    int off = tid * 16 + c * 8192;
    int row = off >> 7;                 // 0..255 across c
    int col = (off & 127) ^ ((row & 7) << 4);
    gload_lds16(Bbase + (size_t)row * 1536 + kt * 128 + col,
                dst + c * 8192 + wavebase);
  };

  // prologue: tiles 0 -> slot 0, 1 -> slot 1  (6 loads each, tile-0 oldest)
  stageA(0, (char*)ldsA[0]);
  #pragma unroll
  for (int c = 0; c < 4; ++c) stageBq(0, (char*)ldsB[0], c);
  stageA(1, (char*)ldsA[1]);
  #pragma unroll
  for (int c = 0; c < 4; ++c) stageBq(1, (char*)ldsB[1], c);
  asm volatile("s_waitcnt vmcnt(6)" ::: "memory");   // tile 0 landed
  __builtin_amdgcn_s_barrier();

  #pragma unroll
  for (int t = 0; t < 12; ++t) {
    const char* As = (const char*)ldsA[t % 3];
    const char* Bs = (const char*)ldsB[t % 3];
    char* dA = (char*)ldsA[(t + 2) % 3];
    char* dB = (char*)ldsB[(t + 2) % 3];
    const int st = t + 2;
    half8 breg[4][2];
    #pragma unroll
    for (int p = 0; p < 2; ++p) {
      half8 areg[2][2];
      #pragma unroll
      for (int dmi = 0; dmi < 2; ++dmi) {
        int row = wr * 64 + (p * 2 + dmi) * 16 + m;
        #pragma unroll
        for (int ks = 0; ks < 2; ++ks)
          areg[dmi][ks] = *(const half8*)(As + row * 128 +
                                          ((ks * 64 + q * 16) ^ ((m & 7) << 4)));
      }
      if (p == 0) {
        #pragma unroll
        for (int ni = 0; ni < 4; ++ni) {
          int row = wc * 64 + ni * 16 + m;
          #pragma unroll
          for (int ks = 0; ks < 2; ++ks)
            breg[ni][ks] = *(const half8*)(Bs + row * 128 +
                                           ((ks * 64 + q * 16) ^ ((m & 7) << 4)));
        }
      }
      if (st < 12) {
        if (p == 0) { stageA(st, dA); stageBq(st, dB, 0); }
        else        { stageBq(st, dB, 1); stageBq(st, dB, 2); stageBq(st, dB, 3); }
      }
      if (p == 1) {
        if (t < 10)       asm volatile("s_waitcnt vmcnt(6)" ::: "memory");
        else if (t == 10) asm volatile("s_waitcnt vmcnt(0)" ::: "memory");
      }
      __builtin_amdgcn_s_barrier();
      asm volatile("s_waitcnt lgkmcnt(0)" ::: "memory");
      __builtin_amdgcn_s_setprio(1);
      #pragma unroll
      for (int ks = 0; ks < 2; ++ks)
        #pragma unroll
        for (int dmi = 0; dmi < 2; ++dmi)
          #pragma unroll
          for (int ni = 0; ni < 4; ++ni)
            acc[p * 2 + dmi][ni] = __builtin_amdgcn_mfma_f32_16x16x32_f16(
                areg[dmi][ks], breg[ni][ks], acc[p * 2 + dmi][ni], 0, 0, 0);
      __builtin_amdgcn_s_setprio(0);
      __builtin_amdgcn_s_barrier();
    }
  }

  // epilogue: score partial = sum_e tanh(acc + b[e]) * c[e]
  float bb[4], cc[4];
  #pragma unroll
  for (int ni = 0; ni < 4; ++ni) {
    int e = ntile * 256 + wc * 64 + ni * 16 + m;
    bb[ni] = bias[e];
    cc[ni] = cvec[e];
  }
  #pragma unroll
  for (int mi = 0; mi < 4; ++mi) {
    #pragma unroll
    for (int j = 0; j < 4; ++j) {
      float s = 0.f;
      #pragma unroll
      for (int ni = 0; ni < 4; ++ni)
        s += tanh_fast(acc[mi][ni][j] + bb[ni]) * cc[ni];
      s += __shfl_xor(s, 1);
      s += __shfl_xor(s, 2);
      s += __shfl_xor(s, 4);
      s += __shfl_xor(s, 8);
      if (m == 0) scpart[wc][wr * 64 + mi * 16 + q * 4 + j] = s;
    }
  }
  __syncthreads();
  if (tid < 128)
    part[ntile * 32768 + mtile * 128 + tid] =
        scpart[0][tid] + scpart[1][tid] + scpart[2][tid] + scpart[3][tid];
}

// ---------------- fused softmax + weighted sum ----------------
__global__ void wsum_fused(const ushort* __restrict__ Ah, const float* __restrict__ prt,
                           float* __restrict__ out) {
  int b = blockIdx.x, dc = blockIdx.y;   // grid (64,3), 128 threads
  int t = threadIdx.x;
  __shared__ float w[512];
  __shared__ float redm[2], reds[2];

  float s[4];
  #pragma unroll
  for (int i = 0; i < 4; ++i) {
    int r = b * 512 + t + i * 128;
    s[i] = prt[r] + prt[32768 + r] + prt[2 * 32768 + r];
  }
  float mx = fmaxf(fmaxf(s[0], s[1]), fmaxf(s[2], s[3]));
  #pragma unroll
  for (int o = 32; o >= 1; o >>= 1) mx = fmaxf(mx, __shfl_xor(mx, o));
  if ((t & 63) == 0) redm[t >> 6] = mx;
  __syncthreads();
  mx = fmaxf(redm[0], redm[1]);

  float e[4], sm = 0.f;
  #pragma unroll
  for (int i = 0; i < 4; ++i) { e[i] = __expf(s[i] - mx); sm += e[i]; }
  #pragma unroll
  for (int o = 32; o >= 1; o >>= 1) sm += __shfl_xor(sm, o);
  if ((t & 63) == 0) reds[t >> 6] = sm;
  __syncthreads();
  float inv = 1.0f / (reds[0] + reds[1]);
  #pragma unroll
  for (int i = 0; i < 4; ++i) w[t + i * 128] = e[i] * inv;
  __syncthreads();

  int d0 = dc * 256 + t * 2;
  const ushort* hp = Ah + (size_t)b * 512 * 768 + d0;
  float a0 = 0.f, a1 = 0.f;
  #pragma unroll 8
  for (int l = 0; l < 512; ++l) {
    unsigned u = *(const unsigned*)(hp + (size_t)l * 768);
    float wl = w[l];
    a0 += wl * (float)__builtin_bit_cast(_Float16, (unsigned short)(u & 0xffff));
    a1 += wl * (float)__builtin_bit_cast(_Float16, (unsigned short)(u >> 16));
  }
  out[b * 768 + d0] = a0;
  out[b * 768 + d0 + 1] = a1;

  if (dc == 0) {
    #pragma unroll
    for (int i = 0; i < 4; ++i)
      out[49152 + b * 512 + t + i * 128] = w[t + i * 128];
  }
}

// ---------------- launch ----------------
extern "C" void kernel_launch(void* const* d_in, const int* in_sizes, int n_in,
                              void* d_out, int out_size, void* d_ws, size_t ws_size,
                              hipStream_t stream) {
  const float* H    = (const float*)d_in[0];
  const float* W    = (const float*)d_in[1];
  const float* bias = (const float*)d_in[2];
  const float* cvec = (const float*)d_in[3];
  float* out = (float*)d_out;

  char* ws = (char*)d_ws;
  ushort* Ah = (ushort*)(ws + 0);              // 50,331,648 B
  ushort* Wt = (ushort*)(ws + 50331648);       //  1,179,648 B
  float*  prt = (float*)(ws + 51511296);       //    393,216 B ([3][32768])

  hipLaunchKernelGGL(convert_h, dim3(24576), dim3(256), 0, stream,
                     (const float4*)H, (ushort4*)Ah);
  hipLaunchKernelGGL(convert_w, dim3(576), dim3(256), 0, stream,
                     (const float4*)W, (ushort4*)Wt);
  hipLaunchKernelGGL(gemm_scores, dim3(768), dim3(512), 0, stream,
                     Ah, Wt, bias, cvec, prt);
  hipLaunchKernelGGL(wsum_fused, dim3(64, 3), dim3(128), 0, stream,
                     Ah, prt, out);
}